// Round 8
// baseline (752.667 us; speedup 1.0000x reference)
//
#include <hip/hip_runtime.h>
#include <hip/hip_bf16.h>
#include <stdint.h>

#define N_ATOMS 65536
#define N_BONDS 131072
#define N_MOLS  512
#define D_IN    16
#define DD      128
#define REPEAT  3
#define PITCH   136   // LDS row pitch (bf16): 2-way max bank aliasing (free)

typedef __attribute__((ext_vector_type(8))) short s8b;
typedef __attribute__((ext_vector_type(4))) float f32x4;

__device__ __forceinline__ float us2f(unsigned short s) {
    unsigned int u = ((unsigned int)s) << 16;
    float f; __builtin_memcpy(&f, &u, 4); return f;
}
__device__ __forceinline__ unsigned short f2us(float f) {
    __hip_bfloat16 h = __float2bfloat16(f);
    unsigned short s; __builtin_memcpy(&s, &h, 2); return s;
}
__device__ __forceinline__ void acc8(float* a, uint4 v) {
    unsigned short w[8]; __builtin_memcpy(w, &v, 16);
#pragma unroll
    for (int j = 0; j < 8; j++) a[j] += us2f(w[j]);
}

// ---------------- one-time prep ----------------

// Pack W[K][128] fp32 -> bf16 fragment order: Wpk[(((c*4+ks)*4+quad)*128 + n)*8 + j]
__global__ void k_pack_w(const float* __restrict__ W, unsigned short* __restrict__ Wpk, int K) {
    int idx = blockIdx.x * 256 + threadIdx.x;     // K*128
    if (idx >= K * 128) return;
    int k = idx >> 7, n = idx & 127;
    int c = k >> 7, ks = (k >> 5) & 3, quad = (k >> 3) & 3, j = k & 7;
    int pidx = (((c * 4 + ks) * 4 + quad) * 128 + n) * 8 + j;
    Wpk[pidx] = f2us(W[k * 128 + n]);
}

__global__ void k_deg(const int* __restrict__ bsrc, const int* __restrict__ bdst,
                      int* __restrict__ deg) {
    int e = blockIdx.x * 256 + threadIdx.x;
    atomicAdd(&deg[bsrc[e]], 1);
    atomicAdd(&deg[bdst[e]], 1);
}

__global__ void k_scan(const int* __restrict__ deg, int* __restrict__ rowptr,
                       int* __restrict__ cursor) {
    __shared__ int part[1024];
    int t = threadIdx.x;
    int base = t * 64;
    int s = 0;
    for (int i = 0; i < 64; i++) s += deg[base + i];
    part[t] = s;
    __syncthreads();
    if (t == 0) {
        int run = 0;
        for (int i = 0; i < 1024; i++) { int v = part[i]; part[i] = run; run += v; }
    }
    __syncthreads();
    int off = part[t];
    for (int i = 0; i < 64; i++) {
        rowptr[base + i] = off;
        cursor[base + i] = off;
        off += deg[base + i];
    }
    if (t == 1023) rowptr[N_ATOMS] = off;
}

__global__ void k_fill(const int* __restrict__ bsrc, const int* __restrict__ bdst,
                       int* __restrict__ cursor, int* __restrict__ adj) {
    int e = blockIdx.x * 256 + threadIdx.x;
    int p = atomicAdd(&cursor[bsrc[e]], 1); adj[p] = e;
    int q = atomicAdd(&cursor[bdst[e]], 1); adj[q] = e;
}

__global__ void k_molptr(const int* __restrict__ ids, int rows, int* __restrict__ mptr) {
    int m = threadIdx.x;
    if (m > N_MOLS) return;
    int lo = 0, hi = rows;
    while (lo < hi) {
        int mid = (lo + hi) >> 1;
        if (ids[mid] < m) lo = mid + 1; else hi = mid;
    }
    mptr[m] = lo;
}

// ---------------- init ----------------

__global__ void k_init_edges(const float* __restrict__ bo, const float* __restrict__ Wfe,
                             const float* __restrict__ bfe, unsigned short* __restrict__ he) {
    int idx = blockIdx.x * 256 + threadIdx.x;
    int e = idx >> 7, d = idx & 127;
    he[idx] = f2us(fmaxf(fmaf(bo[e], Wfe[d], bfe[d]), 0.f));
}

__global__ void k_init_nodes(const float* __restrict__ atoms, const float* __restrict__ Wfv,
                             const float* __restrict__ bfv,
                             unsigned short* __restrict__ hv, unsigned short* __restrict__ hv0) {
    int idx = blockIdx.x * 256 + threadIdx.x;
    int n = idx >> 7, d = idx & 127;
    float acc = bfv[d];
#pragma unroll
    for (int k = 0; k < D_IN; k++)
        acc = fmaf(atoms[n*D_IN + k], Wfv[k*DD + d], acc);
    unsigned short v = f2us(fmaxf(acc, 0.f));
    hv[idx] = v; hv0[idx] = v;
}

// split per-molecule sum: S sub-ranges per mol; one atomic per col per block.
__global__ __launch_bounds__(256) void k_molsum_s(const unsigned short* __restrict__ x,
                                                  const int* __restrict__ mptr,
                                                  float* __restrict__ out, int S) {
    __shared__ float red[16 * 128];
    int m = blockIdx.x / S, s = blockIdx.x - m * S;
    int b = mptr[m], e = mptr[m + 1];
    int len = (e - b + S - 1) / S;
    int r0 = b + s * len;
    int r1 = min(r0 + len, e);
    int rl = threadIdx.x >> 4, g = threadIdx.x & 15;
    float acc[8] = {0,0,0,0,0,0,0,0};
    for (int r = r0 + rl; r < r1; r += 16)
        acc8(acc, *reinterpret_cast<const uint4*>(x + (size_t)r * DD + g * 8));
#pragma unroll
    for (int j = 0; j < 8; j++) red[rl * 128 + g * 8 + j] = acc[j];
    __syncthreads();
    if (threadIdx.x < 128) {
        int col = threadIdx.x;
        float sum = 0.f;
#pragma unroll
        for (int i = 0; i < 16; i++) sum += red[i * 128 + col];
        atomicAdd(&out[(size_t)m * DD + col], sum);
    }
}

__global__ void k_mol_init(const float* __restrict__ ns, const float* __restrict__ Wfu,
                           const float* __restrict__ bfu, float* __restrict__ hu0) {
    int idx = blockIdx.x * 256 + threadIdx.x;
    int m = idx >> 7, d = idx & 127;
    float acc = bfu[d];
    for (int k = 0; k < DD; k++)
        acc = fmaf(ns[m*DD + k], Wfu[k*DD + d], acc);
    hu0[idx] = fmaxf(acc, 0.f);
}

// fused tiny GEMMs: yue[m][d] = be[d] + hu[m]·We[512:640]; yuv[m][d] = bv[d] + hu[m]·Wv[384:512]
__global__ void k_yrow2(const float* __restrict__ hu,
                        const float* __restrict__ We, const float* __restrict__ be,
                        const float* __restrict__ Wv, const float* __restrict__ bv,
                        float* __restrict__ yue, float* __restrict__ yuv) {
    int idx = blockIdx.x * 256 + threadIdx.x;   // 2*M*D
    int half = idx >= N_MOLS * DD;
    int md = half ? idx - N_MOLS * DD : idx;
    int m = md >> 7, d = md & 127;
    const float* W  = half ? Wv + 384 * DD : We + 512 * DD;
    float acc = half ? bv[d] : be[d];
    for (int k = 0; k < DD; k++)
        acc = fmaf(hu[m*DD + k], W[k*DD + d], acc);
    (half ? yuv : yue)[md] = acc;
}

// ---------------- phi_e (MFMA, LDS staging + reg-prefetch, he0 recomputed) ----------------
// he[e] <- relu([h_e | h_e0(recomp) | h_v[src] | h_v[dst]] @ We[0:512] + yue[bmol[e]]), in place.
__global__ __launch_bounds__(256) void k_phi_e(
        unsigned short* __restrict__ he,
        const float* __restrict__ bo, const float* __restrict__ Wfe,
        const float* __restrict__ bfe,
        const unsigned short* __restrict__ hv,
        const unsigned short* __restrict__ Wpk, const float* __restrict__ yue,
        const int* __restrict__ bsrc, const int* __restrict__ bdst,
        const int* __restrict__ bmol) {
    __shared__ __align__(16) unsigned short xs[128 * PITCH];
    __shared__ int ssrc[128], sdst[128];
    __shared__ float sbo[128];
    int tid = threadIdx.x;
    int e0 = blockIdx.x * 128;
    if (tid < 128) {
        ssrc[tid] = bsrc[e0 + tid];
        sdst[tid] = bdst[e0 + tid];
        sbo[tid]  = bo[e0 + tid];
    }
    int wv = tid >> 6, lane = tid & 63, quad = lane >> 4, l15 = lane & 15;
    f32x4 acc[8][2];
#pragma unroll
    for (int mt = 0; mt < 8; mt++) {
        acc[mt][0] = (f32x4){0.f, 0.f, 0.f, 0.f};
        acc[mt][1] = (f32x4){0.f, 0.f, 0.f, 0.f};
    }

    uint4 pf[8];
    auto prefetch = [&](int c) {
#pragma unroll
        for (int t = 0; t < 8; t++) {
            int u = tid + t * 256;
            int i = u >> 4, g = (u & 15) * 8;
            const unsigned short* src = (c == 0) ? he + (size_t)(e0 + i) * DD
                                      : (c == 2) ? hv + (size_t)ssrc[i] * DD
                                                 : hv + (size_t)sdst[i] * DD;
            pf[t] = *reinterpret_cast<const uint4*>(src + g);
        }
    };

    auto mfma_chunk = [&](int WC) {
#pragma unroll
        for (int ks = 0; ks < 4; ks++) {
            const unsigned short* wb = Wpk + ((WC * 4 + ks) * 4 + quad) * 1024 + (wv * 32 + l15) * 8;
            s8b b0 = *reinterpret_cast<const s8b*>(wb);
            s8b b1 = *reinterpret_cast<const s8b*>(wb + 128);
#pragma unroll
            for (int mt = 0; mt < 8; mt++) {
                s8b afr = *reinterpret_cast<const s8b*>(&xs[(mt*16 + l15) * PITCH + ks*32 + quad*8]);
                acc[mt][0] = __builtin_amdgcn_mfma_f32_16x16x32_bf16(afr, b0, acc[mt][0], 0, 0, 0);
                acc[mt][1] = __builtin_amdgcn_mfma_f32_16x16x32_bf16(afr, b1, acc[mt][1], 0, 0, 0);
            }
        }
    };

    prefetch(0);                  // he rows in flight (no ssrc dependency)
    __syncthreads();              // sbo/ssrc/sdst visible
    // stage chunk 1 (he0 recomputed, zero global loads) while pf(0) is in flight
#pragma unroll
    for (int t = 0; t < 8; t++) {
        int u = tid + t * 256;
        int i = u >> 4, g = (u & 15) * 8;
        float b = sbo[i];
        unsigned short tmp[8];
#pragma unroll
        for (int j = 0; j < 8; j++)
            tmp[j] = f2us(fmaxf(fmaf(b, Wfe[g + j], bfe[g + j]), 0.f));
        uint4 val; __builtin_memcpy(&val, tmp, 16);
        *reinterpret_cast<uint4*>(&xs[i * PITCH + g]) = val;
    }
    __syncthreads();
    mfma_chunk(1);

    const int clist[3] = {0, 2, 3};
#pragma unroll
    for (int idx = 0; idx < 3; idx++) {
        __syncthreads();          // xs free
#pragma unroll
        for (int t = 0; t < 8; t++) {
            int u = tid + t * 256;
            int i = u >> 4, g = (u & 15) * 8;
            *reinterpret_cast<uint4*>(&xs[i * PITCH + g]) = pf[t];
        }
        __syncthreads();          // xs ready
        if (idx < 2) prefetch(clist[idx + 1]);
        mfma_chunk(clist[idx]);
    }

    // epilogue: C/D layout col=lane&15, row=quad*4+reg; += yue[bmol], relu, store in place
#pragma unroll
    for (int mt = 0; mt < 8; mt++) {
#pragma unroll
        for (int r = 0; r < 4; r++) {
            int row = e0 + mt*16 + quad*4 + r;
            const float* yrow = yue + (size_t)bmol[row] * DD;
#pragma unroll
            for (int nt = 0; nt < 2; nt++) {
                int col = wv*32 + nt*16 + l15;
                float v = acc[mt][nt][r] + yrow[col];
                he[(size_t)row * DD + col] = f2us(fmaxf(v, 0.f));
            }
        }
    }
}

// ---------------- e_bar_i gather (CSR, vectorized, unroll-4) ----------------
__global__ __launch_bounds__(256) void k_ebar(const unsigned short* __restrict__ he,
                                              const int* __restrict__ rowptr,
                                              const int* __restrict__ adj,
                                              unsigned short* __restrict__ ebar_i) {
    int n = blockIdx.x * 16 + (threadIdx.x >> 4);
    int g = threadIdx.x & 15;
    int b = rowptr[n], e = rowptr[n + 1];
    float acc[8] = {0,0,0,0,0,0,0,0};
    int j = b;
    for (; j + 3 < e; j += 4) {
        uint4 v0 = *reinterpret_cast<const uint4*>(he + (size_t)adj[j]     * DD + g * 8);
        uint4 v1 = *reinterpret_cast<const uint4*>(he + (size_t)adj[j + 1] * DD + g * 8);
        uint4 v2 = *reinterpret_cast<const uint4*>(he + (size_t)adj[j + 2] * DD + g * 8);
        uint4 v3 = *reinterpret_cast<const uint4*>(he + (size_t)adj[j + 3] * DD + g * 8);
        acc8(acc, v0); acc8(acc, v1); acc8(acc, v2); acc8(acc, v3);
    }
    for (; j < e; j++)
        acc8(acc, *reinterpret_cast<const uint4*>(he + (size_t)adj[j] * DD + g * 8));
    unsigned short o[8];
#pragma unroll
    for (int k = 0; k < 8; k++) o[k] = f2us(acc[k]);
    uint4 ov; __builtin_memcpy(&ov, o, 16);
    *reinterpret_cast<uint4*>(ebar_i + (size_t)n * DD + g * 8) = ov;
}

// ---------------- phi_v (MFMA, LDS staging + reg-prefetch, 3 chunks) ----------------
// hv[n] <- relu([h_v | h_v0 | ebar_i] @ Wv[0:384] + yuv[amol[n]]), in place.
__global__ __launch_bounds__(256) void k_phi_v(
        unsigned short* __restrict__ hv, const unsigned short* __restrict__ hv0,
        const unsigned short* __restrict__ ebar_i,
        const unsigned short* __restrict__ Wpk, const float* __restrict__ yuv,
        const int* __restrict__ amol) {
    __shared__ __align__(16) unsigned short xs[128 * PITCH];
    int tid = threadIdx.x;
    int n0 = blockIdx.x * 128;
    int wv = tid >> 6, lane = tid & 63, quad = lane >> 4, l15 = lane & 15;
    f32x4 acc[8][2];
#pragma unroll
    for (int mt = 0; mt < 8; mt++) {
        acc[mt][0] = (f32x4){0.f, 0.f, 0.f, 0.f};
        acc[mt][1] = (f32x4){0.f, 0.f, 0.f, 0.f};
    }

    const unsigned short* bases[3] = {
        hv + (size_t)n0 * DD, hv0 + (size_t)n0 * DD, ebar_i + (size_t)n0 * DD
    };

    uint4 pf[8];
    auto prefetch = [&](int c) {
        const unsigned short* xb = bases[c];
#pragma unroll
        for (int t = 0; t < 8; t++) {
            int u = tid + t * 256;
            int i = u >> 4, g = (u & 15) * 8;
            pf[t] = *reinterpret_cast<const uint4*>(xb + (size_t)i * DD + g);
        }
    };

    prefetch(0);
#pragma unroll
    for (int c = 0; c < 3; c++) {
        __syncthreads();
#pragma unroll
        for (int t = 0; t < 8; t++) {
            int u = tid + t * 256;
            int i = u >> 4, g = (u & 15) * 8;
            *reinterpret_cast<uint4*>(&xs[i * PITCH + g]) = pf[t];
        }
        __syncthreads();
        if (c < 2) prefetch(c + 1);
#pragma unroll
        for (int ks = 0; ks < 4; ks++) {
            const unsigned short* wb = Wpk + ((c * 4 + ks) * 4 + quad) * 1024 + (wv * 32 + l15) * 8;
            s8b b0 = *reinterpret_cast<const s8b*>(wb);
            s8b b1 = *reinterpret_cast<const s8b*>(wb + 128);
#pragma unroll
            for (int mt = 0; mt < 8; mt++) {
                s8b afr = *reinterpret_cast<const s8b*>(&xs[(mt*16 + l15) * PITCH + ks*32 + quad*8]);
                acc[mt][0] = __builtin_amdgcn_mfma_f32_16x16x32_bf16(afr, b0, acc[mt][0], 0, 0, 0);
                acc[mt][1] = __builtin_amdgcn_mfma_f32_16x16x32_bf16(afr, b1, acc[mt][1], 0, 0, 0);
            }
        }
    }

#pragma unroll
    for (int mt = 0; mt < 8; mt++) {
#pragma unroll
        for (int r = 0; r < 4; r++) {
            int row = n0 + mt*16 + quad*4 + r;
            const float* yrow = yuv + (size_t)amol[row] * DD;
#pragma unroll
            for (int nt = 0; nt < 2; nt++) {
                int col = wv*32 + nt*16 + l15;
                float v = acc[mt][nt][r] + yrow[col];
                hv[(size_t)row * DD + col] = f2us(fmaxf(v, 0.f));
            }
        }
    }
}

// ---------------- phi_u ----------------
__global__ void k_phi_u(const float* __restrict__ hu_in, const float* __restrict__ hu0,
                        const float* __restrict__ ebar, const float* __restrict__ vbar,
                        const float* __restrict__ Wu, const float* __restrict__ bu,
                        float* __restrict__ hu_out, float* __restrict__ dout) {
    int idx = blockIdx.x * 256 + threadIdx.x;
    int m = idx >> 7, d = idx & 127;
    float acc = bu[d];
    const float* segs[4] = { hu_in + m*DD, hu0 + m*DD, ebar + m*DD, vbar + m*DD };
    for (int s = 0; s < 4; s++) {
        const float* x = segs[s];
        const float* W = Wu + (s*DD)*DD + d;
        for (int k = 0; k < DD; k++)
            acc = fmaf(x[k], W[k*DD], acc);
    }
    float v = fmaxf(acc, 0.f);
    hu_out[idx] = v;
    dout[idx] = v;
}

// ---------------- launch ----------------

extern "C" void kernel_launch(void* const* d_in, const int* in_sizes, int n_in,
                              void* d_out, int out_size, void* d_ws, size_t ws_size,
                              hipStream_t stream) {
    const float* atoms = (const float*)d_in[0];
    const float* bo    = (const float*)d_in[1];
    const float* Wfe   = (const float*)d_in[2];
    const float* bfe   = (const float*)d_in[3];
    const float* Wfv   = (const float*)d_in[4];
    const float* bfv   = (const float*)d_in[5];
    const float* Wfu   = (const float*)d_in[6];
    const float* bfu   = (const float*)d_in[7];
    const float* We    = (const float*)d_in[8];
    const float* be    = (const float*)d_in[9];
    const float* Wv    = (const float*)d_in[10];
    const float* bv    = (const float*)d_in[11];
    const float* Wu    = (const float*)d_in[12];
    const float* bu    = (const float*)d_in[13];
    const int* bsrc    = (const int*)d_in[14];
    const int* bdst    = (const int*)d_in[15];
    const int* amol    = (const int*)d_in[16];
    const int* bmol    = (const int*)d_in[17];

    char* p = (char*)d_ws;
    auto alloc = [&](size_t bytes) {
        char* r = p;
        p += (bytes + 255) & ~(size_t)255;
        return r;
    };
    unsigned short* he     = (unsigned short*)alloc((size_t)N_BONDS * DD * 2);
    unsigned short* hv     = (unsigned short*)alloc((size_t)N_ATOMS * DD * 2);
    unsigned short* hv0b   = (unsigned short*)alloc((size_t)N_ATOMS * DD * 2);
    unsigned short* ebar_i = (unsigned short*)alloc((size_t)N_ATOMS * DD * 2);
    unsigned short* WeP    = (unsigned short*)alloc((size_t)640 * DD * 2);
    unsigned short* WvP    = (unsigned short*)alloc((size_t)512 * DD * 2);
    int* deg      = (int*)alloc((size_t)N_ATOMS * 4);
    int* rowptr   = (int*)alloc((size_t)(N_ATOMS + 1) * 4);
    int* cursor   = (int*)alloc((size_t)N_ATOMS * 4);
    int* adj      = (int*)alloc((size_t)2 * N_BONDS * 4);
    int* bmol_ptr = (int*)alloc((size_t)(N_MOLS + 1) * 4);
    int* amol_ptr = (int*)alloc((size_t)(N_MOLS + 1) * 4);
    float* node_sum = (float*)alloc((size_t)N_MOLS * DD * 4);
    float* hu0   = (float*)alloc((size_t)N_MOLS * DD * 4);
    float* huA   = (float*)alloc((size_t)N_MOLS * DD * 4);
    float* huB   = (float*)alloc((size_t)N_MOLS * DD * 4);
    float* ebar  = (float*)alloc((size_t)N_MOLS * DD * 4);
    float* vbar  = (float*)alloc((size_t)N_MOLS * DD * 4);
    float* yue   = (float*)alloc((size_t)N_MOLS * DD * 4);
    float* yuv   = (float*)alloc((size_t)N_MOLS * DD * 4);

    // ---- CSR + mol ranges ----
    hipMemsetAsync(deg, 0, (size_t)N_ATOMS * 4, stream);
    k_deg<<<N_BONDS/256, 256, 0, stream>>>(bsrc, bdst, deg);
    k_scan<<<1, 1024, 0, stream>>>(deg, rowptr, cursor);
    k_fill<<<N_BONDS/256, 256, 0, stream>>>(bsrc, bdst, cursor, adj);
    k_molptr<<<1, 1024, 0, stream>>>(bmol, N_BONDS, bmol_ptr);
    k_molptr<<<1, 1024, 0, stream>>>(amol, N_ATOMS, amol_ptr);

    // ---- weight packing ----
    k_pack_w<<<(640*DD)/256, 256, 0, stream>>>(We, WeP, 640);
    k_pack_w<<<(512*DD)/256, 256, 0, stream>>>(Wv, WvP, 512);

    // ---- init ----
    k_init_edges<<<(N_BONDS*DD)/256, 256, 0, stream>>>(bo, Wfe, bfe, he);
    k_init_nodes<<<(N_ATOMS*DD)/256, 256, 0, stream>>>(atoms, Wfv, bfv, hv, hv0b);
    hipMemsetAsync(node_sum, 0, (size_t)N_MOLS * DD * 4, stream);
    k_molsum_s<<<N_MOLS*2, 256, 0, stream>>>(hv, amol_ptr, node_sum, 2);
    k_mol_init<<<(N_MOLS*DD)/256, 256, 0, stream>>>(node_sum, Wfu, bfu, hu0);

    const float* hu_in = hu0; float* hu_out = huA;

    for (int r = 0; r < REPEAT; r++) {
        k_yrow2<<<(2*N_MOLS*DD)/256, 256, 0, stream>>>(hu_in, We, be, Wv, bv, yue, yuv);
        hipMemsetAsync(ebar, 0, (size_t)N_MOLS * DD * 4, stream);
        hipMemsetAsync(vbar, 0, (size_t)N_MOLS * DD * 4, stream);

        k_phi_e<<<N_BONDS/128, 256, 0, stream>>>(he, bo, Wfe, bfe, hv, WeP, yue,
                                                 bsrc, bdst, bmol);
        k_ebar<<<N_ATOMS/16, 256, 0, stream>>>(he, rowptr, adj, ebar_i);
        k_molsum_s<<<N_MOLS*4, 256, 0, stream>>>(he, bmol_ptr, ebar, 4);
        k_phi_v<<<N_ATOMS/128, 256, 0, stream>>>(hv, hv0b, ebar_i, WvP, yuv, amol);
        k_molsum_s<<<N_MOLS*2, 256, 0, stream>>>(hv, amol_ptr, vbar, 2);
        k_phi_u<<<(N_MOLS*DD)/256, 256, 0, stream>>>(hu_in, hu0, ebar, vbar, Wu, bu,
                                                     hu_out, (float*)d_out);

        hu_in = hu_out; hu_out = (hu_out == huA) ? huB : huA;
    }
}

// Round 9
// 597.223 us; speedup vs baseline: 1.2603x; 1.2603x over previous
//
#include <hip/hip_runtime.h>
#include <hip/hip_bf16.h>
#include <stdint.h>

#define N_ATOMS 65536
#define N_BONDS 131072
#define N_MOLS  512
#define D_IN    16
#define DD      128
#define REPEAT  3
#define PITCH   136   // LDS row pitch (bf16): 2-way max bank aliasing (free)

typedef __attribute__((ext_vector_type(8))) short s8b;
typedef __attribute__((ext_vector_type(4))) float f32x4;

__device__ __forceinline__ float us2f(unsigned short s) {
    unsigned int u = ((unsigned int)s) << 16;
    float f; __builtin_memcpy(&f, &u, 4); return f;
}
__device__ __forceinline__ unsigned short f2us(float f) {
    __hip_bfloat16 h = __float2bfloat16(f);
    unsigned short s; __builtin_memcpy(&s, &h, 2); return s;
}
__device__ __forceinline__ void acc8(float* a, uint4 v) {
    unsigned short w[8]; __builtin_memcpy(w, &v, 16);
#pragma unroll
    for (int j = 0; j < 8; j++) a[j] += us2f(w[j]);
}

// ---------------- one-time prep ----------------

// Pack W[K][128] fp32 -> bf16 fragment order: Wpk[(((c*4+ks)*4+quad)*128 + n)*8 + j]
__global__ void k_pack_w(const float* __restrict__ W, unsigned short* __restrict__ Wpk, int K) {
    int idx = blockIdx.x * 256 + threadIdx.x;     // K*128
    if (idx >= K * 128) return;
    int k = idx >> 7, n = idx & 127;
    int c = k >> 7, ks = (k >> 5) & 3, quad = (k >> 3) & 3, j = k & 7;
    int pidx = (((c * 4 + ks) * 4 + quad) * 128 + n) * 8 + j;
    Wpk[pidx] = f2us(W[k * 128 + n]);
}

__global__ void k_deg(const int* __restrict__ bsrc, const int* __restrict__ bdst,
                      int* __restrict__ deg) {
    int e = blockIdx.x * 256 + threadIdx.x;
    atomicAdd(&deg[bsrc[e]], 1);
    atomicAdd(&deg[bdst[e]], 1);
}

__global__ void k_scan(const int* __restrict__ deg, int* __restrict__ rowptr,
                       int* __restrict__ cursor) {
    __shared__ int part[1024];
    int t = threadIdx.x;
    int base = t * 64;
    int s = 0;
    for (int i = 0; i < 64; i++) s += deg[base + i];
    part[t] = s;
    __syncthreads();
    if (t == 0) {
        int run = 0;
        for (int i = 0; i < 1024; i++) { int v = part[i]; part[i] = run; run += v; }
    }
    __syncthreads();
    int off = part[t];
    for (int i = 0; i < 64; i++) {
        rowptr[base + i] = off;
        cursor[base + i] = off;
        off += deg[base + i];
    }
    if (t == 1023) rowptr[N_ATOMS] = off;
}

__global__ void k_fill(const int* __restrict__ bsrc, const int* __restrict__ bdst,
                       int* __restrict__ cursor, int* __restrict__ adj) {
    int e = blockIdx.x * 256 + threadIdx.x;
    int p = atomicAdd(&cursor[bsrc[e]], 1); adj[p] = e;
    int q = atomicAdd(&cursor[bdst[e]], 1); adj[q] = e;
}

__global__ void k_molptr(const int* __restrict__ ids, int rows, int* __restrict__ mptr) {
    int m = threadIdx.x;
    if (m > N_MOLS) return;
    int lo = 0, hi = rows;
    while (lo < hi) {
        int mid = (lo + hi) >> 1;
        if (ids[mid] < m) lo = mid + 1; else hi = mid;
    }
    mptr[m] = lo;
}

// ---------------- init ----------------

__global__ void k_init_edges(const float* __restrict__ bo, const float* __restrict__ Wfe,
                             const float* __restrict__ bfe, unsigned short* __restrict__ he) {
    int idx = blockIdx.x * 256 + threadIdx.x;
    int e = idx >> 7, d = idx & 127;
    he[idx] = f2us(fmaxf(fmaf(bo[e], Wfe[d], bfe[d]), 0.f));
}

__global__ void k_init_nodes(const float* __restrict__ atoms, const float* __restrict__ Wfv,
                             const float* __restrict__ bfv, unsigned short* __restrict__ hv,
                             float* __restrict__ node_sum) {
    int idx = blockIdx.x * 256 + threadIdx.x;
    if (idx < N_MOLS * DD) node_sum[idx] = 0.f;      // zero for molsum accumulate
    int n = idx >> 7, d = idx & 127;
    float acc = bfv[d];
#pragma unroll
    for (int k = 0; k < D_IN; k++)
        acc = fmaf(atoms[n*D_IN + k], Wfv[k*DD + d], acc);
    hv[idx] = f2us(fmaxf(acc, 0.f));
}

// split per-molecule sum: S sub-ranges per mol; one atomic per col per block.
__global__ __launch_bounds__(256) void k_molsum_s(const unsigned short* __restrict__ x,
                                                  const int* __restrict__ mptr,
                                                  float* __restrict__ out, int S) {
    __shared__ float red[16 * 128];
    int m = blockIdx.x / S, s = blockIdx.x - m * S;
    int b = mptr[m], e = mptr[m + 1];
    int len = (e - b + S - 1) / S;
    int r0 = b + s * len;
    int r1 = min(r0 + len, e);
    int rl = threadIdx.x >> 4, g = threadIdx.x & 15;
    float acc[8] = {0,0,0,0,0,0,0,0};
    for (int r = r0 + rl; r < r1; r += 16)
        acc8(acc, *reinterpret_cast<const uint4*>(x + (size_t)r * DD + g * 8));
#pragma unroll
    for (int j = 0; j < 8; j++) red[rl * 128 + g * 8 + j] = acc[j];
    __syncthreads();
    if (threadIdx.x < 128) {
        int col = threadIdx.x;
        float sum = 0.f;
#pragma unroll
        for (int i = 0; i < 16; i++) sum += red[i * 128 + col];
        atomicAdd(&out[(size_t)m * DD + col], sum);
    }
}

__global__ void k_mol_init(const float* __restrict__ ns, const float* __restrict__ Wfu,
                           const float* __restrict__ bfu, float* __restrict__ hu0) {
    int idx = blockIdx.x * 256 + threadIdx.x;
    int m = idx >> 7, d = idx & 127;
    float acc = bfu[d];
    for (int k = 0; k < DD; k++)
        acc = fmaf(ns[m*DD + k], Wfu[k*DD + d], acc);
    hu0[idx] = fmaxf(acc, 0.f);
}

// fused per-round: zero ebar/vbar + tiny GEMMs yue/yuv
__global__ void k_yrow2(const float* __restrict__ hu,
                        const float* __restrict__ We, const float* __restrict__ be,
                        const float* __restrict__ Wv, const float* __restrict__ bv,
                        float* __restrict__ yue, float* __restrict__ yuv,
                        float* __restrict__ ebar, float* __restrict__ vbar) {
    int idx = blockIdx.x * 256 + threadIdx.x;   // 2*M*D
    if (idx < N_MOLS * DD) ebar[idx] = 0.f;
    else                   vbar[idx - N_MOLS * DD] = 0.f;
    int half = idx >= N_MOLS * DD;
    int md = half ? idx - N_MOLS * DD : idx;
    int m = md >> 7, d = md & 127;
    const float* W  = half ? Wv + 384 * DD : We + 512 * DD;
    float acc = half ? bv[d] : be[d];
    for (int k = 0; k < DD; k++)
        acc = fmaf(hu[m*DD + k], W[k*DD + d], acc);
    (half ? yuv : yue)[md] = acc;
}

// ---------------- one-time: ye0 = he0 @ We[128:256], he0 recomputed rank-1 ----------------
__global__ __launch_bounds__(256) void k_ye0(
        const float* __restrict__ bo, const float* __restrict__ Wfe,
        const float* __restrict__ bfe, const unsigned short* __restrict__ Wpk,
        unsigned short* __restrict__ ye0) {
    __shared__ __align__(16) unsigned short xs[128 * PITCH];
    __shared__ float sbo[128];
    int tid = threadIdx.x;
    int e0 = blockIdx.x * 128;
    if (tid < 128) sbo[tid] = bo[e0 + tid];
    int wv = tid >> 6, lane = tid & 63, quad = lane >> 4, l15 = lane & 15;
    f32x4 acc[8][2];
#pragma unroll
    for (int mt = 0; mt < 8; mt++) {
        acc[mt][0] = (f32x4){0.f,0.f,0.f,0.f};
        acc[mt][1] = (f32x4){0.f,0.f,0.f,0.f};
    }
    __syncthreads();
    for (int t = 0; t < 8; t++) {
        int u = tid + t * 256;
        int i = u >> 4, g = (u & 15) * 8;
        float b = sbo[i];
        unsigned short tmp[8];
#pragma unroll
        for (int j = 0; j < 8; j++)
            tmp[j] = f2us(fmaxf(fmaf(b, Wfe[g + j], bfe[g + j]), 0.f));
        uint4 val; __builtin_memcpy(&val, tmp, 16);
        *reinterpret_cast<uint4*>(&xs[i * PITCH + g]) = val;
    }
    __syncthreads();
#pragma unroll
    for (int ks = 0; ks < 4; ks++) {
        const unsigned short* wb = Wpk + ((1 * 4 + ks) * 4 + quad) * 1024 + (wv * 32 + l15) * 8;
        s8b b0 = *reinterpret_cast<const s8b*>(wb);
        s8b b1 = *reinterpret_cast<const s8b*>(wb + 128);
#pragma unroll
        for (int mt = 0; mt < 8; mt++) {
            s8b afr = *reinterpret_cast<const s8b*>(&xs[(mt*16 + l15) * PITCH + ks*32 + quad*8]);
            acc[mt][0] = __builtin_amdgcn_mfma_f32_16x16x32_bf16(afr, b0, acc[mt][0], 0, 0, 0);
            acc[mt][1] = __builtin_amdgcn_mfma_f32_16x16x32_bf16(afr, b1, acc[mt][1], 0, 0, 0);
        }
    }
#pragma unroll
    for (int mt = 0; mt < 8; mt++)
#pragma unroll
        for (int r = 0; r < 4; r++) {
            int row = e0 + mt*16 + quad*4 + r;
#pragma unroll
            for (int nt = 0; nt < 2; nt++) {
                int col = wv*32 + nt*16 + l15;
                ye0[(size_t)row * DD + col] = f2us(acc[mt][nt][r]);
            }
        }
}

// ---------------- generic: y = x @ Wpk[chunk wc]  (row-major bf16 out) ----------------
__global__ __launch_bounds__(256) void k_xform(
        const unsigned short* __restrict__ x, const unsigned short* __restrict__ Wpk,
        int wc, unsigned short* __restrict__ y) {
    __shared__ __align__(16) unsigned short xs[128 * PITCH];
    int tid = threadIdx.x;
    int r0 = blockIdx.x * 128;
    int wv = tid >> 6, lane = tid & 63, quad = lane >> 4, l15 = lane & 15;
    f32x4 acc[8][2];
#pragma unroll
    for (int mt = 0; mt < 8; mt++) {
        acc[mt][0] = (f32x4){0.f,0.f,0.f,0.f};
        acc[mt][1] = (f32x4){0.f,0.f,0.f,0.f};
    }
    for (int t = 0; t < 8; t++) {
        int u = tid + t * 256;
        int i = u >> 4, g = (u & 15) * 8;
        *reinterpret_cast<uint4*>(&xs[i * PITCH + g]) =
            *reinterpret_cast<const uint4*>(x + (size_t)(r0 + i) * DD + g);
    }
    __syncthreads();
#pragma unroll
    for (int ks = 0; ks < 4; ks++) {
        const unsigned short* wb = Wpk + ((wc * 4 + ks) * 4 + quad) * 1024 + (wv * 32 + l15) * 8;
        s8b b0 = *reinterpret_cast<const s8b*>(wb);
        s8b b1 = *reinterpret_cast<const s8b*>(wb + 128);
#pragma unroll
        for (int mt = 0; mt < 8; mt++) {
            s8b afr = *reinterpret_cast<const s8b*>(&xs[(mt*16 + l15) * PITCH + ks*32 + quad*8]);
            acc[mt][0] = __builtin_amdgcn_mfma_f32_16x16x32_bf16(afr, b0, acc[mt][0], 0, 0, 0);
            acc[mt][1] = __builtin_amdgcn_mfma_f32_16x16x32_bf16(afr, b1, acc[mt][1], 0, 0, 0);
        }
    }
#pragma unroll
    for (int mt = 0; mt < 8; mt++)
#pragma unroll
        for (int r = 0; r < 4; r++) {
            int row = r0 + mt*16 + quad*4 + r;
#pragma unroll
            for (int nt = 0; nt < 2; nt++) {
                int col = wv*32 + nt*16 + l15;
                y[(size_t)row * DD + col] = f2us(acc[mt][nt][r]);
            }
        }
}

// ---------------- per-round: Zs = hv@We[256:384], Zd = hv@We[384:512] ----------------
__global__ __launch_bounds__(256) void k_zsd(
        const unsigned short* __restrict__ hv, const unsigned short* __restrict__ Wpk,
        unsigned short* __restrict__ Zs, unsigned short* __restrict__ Zd) {
    __shared__ __align__(16) unsigned short xs[128 * PITCH];
    int tid = threadIdx.x;
    int n0 = blockIdx.x * 128;
    int wv = tid >> 6, lane = tid & 63, quad = lane >> 4, l15 = lane & 15;
    f32x4 aS[8][2], aD[8][2];
#pragma unroll
    for (int mt = 0; mt < 8; mt++) {
        aS[mt][0] = (f32x4){0.f,0.f,0.f,0.f}; aS[mt][1] = (f32x4){0.f,0.f,0.f,0.f};
        aD[mt][0] = (f32x4){0.f,0.f,0.f,0.f}; aD[mt][1] = (f32x4){0.f,0.f,0.f,0.f};
    }
    for (int t = 0; t < 8; t++) {
        int u = tid + t * 256;
        int i = u >> 4, g = (u & 15) * 8;
        *reinterpret_cast<uint4*>(&xs[i * PITCH + g]) =
            *reinterpret_cast<const uint4*>(hv + (size_t)(n0 + i) * DD + g);
    }
    __syncthreads();
#pragma unroll
    for (int ks = 0; ks < 4; ks++) {
        const unsigned short* wbS = Wpk + ((2 * 4 + ks) * 4 + quad) * 1024 + (wv * 32 + l15) * 8;
        const unsigned short* wbD = Wpk + ((3 * 4 + ks) * 4 + quad) * 1024 + (wv * 32 + l15) * 8;
        s8b s0 = *reinterpret_cast<const s8b*>(wbS);
        s8b s1 = *reinterpret_cast<const s8b*>(wbS + 128);
        s8b d0 = *reinterpret_cast<const s8b*>(wbD);
        s8b d1 = *reinterpret_cast<const s8b*>(wbD + 128);
#pragma unroll
        for (int mt = 0; mt < 8; mt++) {
            s8b afr = *reinterpret_cast<const s8b*>(&xs[(mt*16 + l15) * PITCH + ks*32 + quad*8]);
            aS[mt][0] = __builtin_amdgcn_mfma_f32_16x16x32_bf16(afr, s0, aS[mt][0], 0, 0, 0);
            aS[mt][1] = __builtin_amdgcn_mfma_f32_16x16x32_bf16(afr, s1, aS[mt][1], 0, 0, 0);
            aD[mt][0] = __builtin_amdgcn_mfma_f32_16x16x32_bf16(afr, d0, aD[mt][0], 0, 0, 0);
            aD[mt][1] = __builtin_amdgcn_mfma_f32_16x16x32_bf16(afr, d1, aD[mt][1], 0, 0, 0);
        }
    }
#pragma unroll
    for (int mt = 0; mt < 8; mt++)
#pragma unroll
        for (int r = 0; r < 4; r++) {
            int row = n0 + mt*16 + quad*4 + r;
#pragma unroll
            for (int nt = 0; nt < 2; nt++) {
                int col = wv*32 + nt*16 + l15;
                Zs[(size_t)row * DD + col] = f2us(aS[mt][nt][r]);
                Zd[(size_t)row * DD + col] = f2us(aD[mt][nt][r]);
            }
        }
}

// ---------------- phi_e: 1 MFMA chunk + gathered epilogue ----------------
// he[e] <- relu( he@We[0:128] + ye0[e] + Zs[src] + Zd[dst] + yue[bmol[e]] ), in place.
__global__ __launch_bounds__(256) void k_phi_e(
        unsigned short* __restrict__ he, const unsigned short* __restrict__ ye0,
        const unsigned short* __restrict__ Zs, const unsigned short* __restrict__ Zd,
        const unsigned short* __restrict__ Wpk, const float* __restrict__ yue,
        const int* __restrict__ bsrc, const int* __restrict__ bdst,
        const int* __restrict__ bmol) {
    __shared__ __align__(16) unsigned short xs[128 * PITCH];
    __shared__ int ssrc[128], sdst[128], smol[128];
    int tid = threadIdx.x;
    int e0 = blockIdx.x * 128;
    if (tid < 128) {
        ssrc[tid] = bsrc[e0 + tid];
        sdst[tid] = bdst[e0 + tid];
        smol[tid] = bmol[e0 + tid];
    }
    int wv = tid >> 6, lane = tid & 63, quad = lane >> 4, l15 = lane & 15;
    f32x4 acc[8][2];
#pragma unroll
    for (int mt = 0; mt < 8; mt++) {
        acc[mt][0] = (f32x4){0.f,0.f,0.f,0.f};
        acc[mt][1] = (f32x4){0.f,0.f,0.f,0.f};
    }
    // stage he rows (no dependency on ssrc)
    for (int t = 0; t < 8; t++) {
        int u = tid + t * 256;
        int i = u >> 4, g = (u & 15) * 8;
        *reinterpret_cast<uint4*>(&xs[i * PITCH + g]) =
            *reinterpret_cast<const uint4*>(he + (size_t)(e0 + i) * DD + g);
    }
    __syncthreads();
#pragma unroll
    for (int ks = 0; ks < 4; ks++) {
        const unsigned short* wb = Wpk + ((0 * 4 + ks) * 4 + quad) * 1024 + (wv * 32 + l15) * 8;
        s8b b0 = *reinterpret_cast<const s8b*>(wb);
        s8b b1 = *reinterpret_cast<const s8b*>(wb + 128);
#pragma unroll
        for (int mt = 0; mt < 8; mt++) {
            s8b afr = *reinterpret_cast<const s8b*>(&xs[(mt*16 + l15) * PITCH + ks*32 + quad*8]);
            acc[mt][0] = __builtin_amdgcn_mfma_f32_16x16x32_bf16(afr, b0, acc[mt][0], 0, 0, 0);
            acc[mt][1] = __builtin_amdgcn_mfma_f32_16x16x32_bf16(afr, b1, acc[mt][1], 0, 0, 0);
        }
    }
    __syncthreads();   // xs free for reuse
    // stage ysum = ye0 + Zs[src] + Zd[dst] + yue[mol] into xs (bf16)
    for (int t = 0; t < 8; t++) {
        int u = tid + t * 256;
        int i = u >> 4, g = (u & 15) * 8;
        float s[8] = {0,0,0,0,0,0,0,0};
        acc8(s, *reinterpret_cast<const uint4*>(ye0 + (size_t)(e0 + i) * DD + g));
        acc8(s, *reinterpret_cast<const uint4*>(Zs  + (size_t)ssrc[i] * DD + g));
        acc8(s, *reinterpret_cast<const uint4*>(Zd  + (size_t)sdst[i] * DD + g));
        const float* yr = yue + (size_t)smol[i] * DD + g;
        float4 y0 = *reinterpret_cast<const float4*>(yr);
        float4 y1 = *reinterpret_cast<const float4*>(yr + 4);
        s[0] += y0.x; s[1] += y0.y; s[2] += y0.z; s[3] += y0.w;
        s[4] += y1.x; s[5] += y1.y; s[6] += y1.z; s[7] += y1.w;
        unsigned short tmp[8];
#pragma unroll
        for (int j = 0; j < 8; j++) tmp[j] = f2us(s[j]);
        uint4 val; __builtin_memcpy(&val, tmp, 16);
        *reinterpret_cast<uint4*>(&xs[i * PITCH + g]) = val;
    }
    __syncthreads();
    // epilogue: C/D layout col=lane&15, row=quad*4+reg
#pragma unroll
    for (int mt = 0; mt < 8; mt++)
#pragma unroll
        for (int r = 0; r < 4; r++) {
            int rl = mt*16 + quad*4 + r;
#pragma unroll
            for (int nt = 0; nt < 2; nt++) {
                int col = wv*32 + nt*16 + l15;
                float v = acc[mt][nt][r] + us2f(xs[rl * PITCH + col]);
                he[(size_t)(e0 + rl) * DD + col] = f2us(fmaxf(v, 0.f));
            }
        }
}

// ---------------- e_bar_i gather (CSR, vectorized, unroll-4) ----------------
__global__ __launch_bounds__(256) void k_ebar(const unsigned short* __restrict__ he,
                                              const int* __restrict__ rowptr,
                                              const int* __restrict__ adj,
                                              unsigned short* __restrict__ ebar_i) {
    int n = blockIdx.x * 16 + (threadIdx.x >> 4);
    int g = threadIdx.x & 15;
    int b = rowptr[n], e = rowptr[n + 1];
    float acc[8] = {0,0,0,0,0,0,0,0};
    int j = b;
    for (; j + 3 < e; j += 4) {
        uint4 v0 = *reinterpret_cast<const uint4*>(he + (size_t)adj[j]     * DD + g * 8);
        uint4 v1 = *reinterpret_cast<const uint4*>(he + (size_t)adj[j + 1] * DD + g * 8);
        uint4 v2 = *reinterpret_cast<const uint4*>(he + (size_t)adj[j + 2] * DD + g * 8);
        uint4 v3 = *reinterpret_cast<const uint4*>(he + (size_t)adj[j + 3] * DD + g * 8);
        acc8(acc, v0); acc8(acc, v1); acc8(acc, v2); acc8(acc, v3);
    }
    for (; j < e; j++)
        acc8(acc, *reinterpret_cast<const uint4*>(he + (size_t)adj[j] * DD + g * 8));
    unsigned short o[8];
#pragma unroll
    for (int k = 0; k < 8; k++) o[k] = f2us(acc[k]);
    uint4 ov; __builtin_memcpy(&ov, o, 16);
    *reinterpret_cast<uint4*>(ebar_i + (size_t)n * DD + g * 8) = ov;
}

// ---------------- phi_v: 2 MFMA chunks + epilogue ----------------
// hv[n] <- relu( hv@Wv[0:128] + ebar_i@Wv[256:384] + yv0[n] + yuv[amol[n]] ), in place.
__global__ __launch_bounds__(256) void k_phi_v(
        unsigned short* __restrict__ hv, const unsigned short* __restrict__ ebar_i,
        const unsigned short* __restrict__ yv0,
        const unsigned short* __restrict__ Wpk, const float* __restrict__ yuv,
        const int* __restrict__ amol) {
    __shared__ __align__(16) unsigned short xs[128 * PITCH];
    __shared__ int smol[128];
    int tid = threadIdx.x;
    int n0 = blockIdx.x * 128;
    if (tid < 128) smol[tid] = amol[n0 + tid];
    int wv = tid >> 6, lane = tid & 63, quad = lane >> 4, l15 = lane & 15;
    f32x4 acc[8][2];
#pragma unroll
    for (int mt = 0; mt < 8; mt++) {
        acc[mt][0] = (f32x4){0.f,0.f,0.f,0.f};
        acc[mt][1] = (f32x4){0.f,0.f,0.f,0.f};
    }
    const unsigned short* bases[2] = { hv + (size_t)n0 * DD, ebar_i + (size_t)n0 * DD };
    const int wcs[2] = {0, 2};
    for (int c = 0; c < 2; c++) {
        if (c) __syncthreads();
        for (int t = 0; t < 8; t++) {
            int u = tid + t * 256;
            int i = u >> 4, g = (u & 15) * 8;
            *reinterpret_cast<uint4*>(&xs[i * PITCH + g]) =
                *reinterpret_cast<const uint4*>(bases[c] + (size_t)i * DD + g);
        }
        __syncthreads();
        int WC = wcs[c];
#pragma unroll
        for (int ks = 0; ks < 4; ks++) {
            const unsigned short* wb = Wpk + ((WC * 4 + ks) * 4 + quad) * 1024 + (wv * 32 + l15) * 8;
            s8b b0 = *reinterpret_cast<const s8b*>(wb);
            s8b b1 = *reinterpret_cast<const s8b*>(wb + 128);
#pragma unroll
            for (int mt = 0; mt < 8; mt++) {
                s8b afr = *reinterpret_cast<const s8b*>(&xs[(mt*16 + l15) * PITCH + ks*32 + quad*8]);
                acc[mt][0] = __builtin_amdgcn_mfma_f32_16x16x32_bf16(afr, b0, acc[mt][0], 0, 0, 0);
                acc[mt][1] = __builtin_amdgcn_mfma_f32_16x16x32_bf16(afr, b1, acc[mt][1], 0, 0, 0);
            }
        }
    }
    __syncthreads();   // reuse xs for ysum
    for (int t = 0; t < 8; t++) {
        int u = tid + t * 256;
        int i = u >> 4, g = (u & 15) * 8;
        float s[8] = {0,0,0,0,0,0,0,0};
        acc8(s, *reinterpret_cast<const uint4*>(yv0 + (size_t)(n0 + i) * DD + g));
        const float* yr = yuv + (size_t)smol[i] * DD + g;
        float4 y0 = *reinterpret_cast<const float4*>(yr);
        float4 y1 = *reinterpret_cast<const float4*>(yr + 4);
        s[0] += y0.x; s[1] += y0.y; s[2] += y0.z; s[3] += y0.w;
        s[4] += y1.x; s[5] += y1.y; s[6] += y1.z; s[7] += y1.w;
        unsigned short tmp[8];
#pragma unroll
        for (int j = 0; j < 8; j++) tmp[j] = f2us(s[j]);
        uint4 val; __builtin_memcpy(&val, tmp, 16);
        *reinterpret_cast<uint4*>(&xs[i * PITCH + g]) = val;
    }
    __syncthreads();
#pragma unroll
    for (int mt = 0; mt < 8; mt++)
#pragma unroll
        for (int r = 0; r < 4; r++) {
            int rl = mt*16 + quad*4 + r;
#pragma unroll
            for (int nt = 0; nt < 2; nt++) {
                int col = wv*32 + nt*16 + l15;
                float v = acc[mt][nt][r] + us2f(xs[rl * PITCH + col]);
                hv[(size_t)(n0 + rl) * DD + col] = f2us(fmaxf(v, 0.f));
            }
        }
}

// ---------------- phi_u ----------------
__global__ void k_phi_u(const float* __restrict__ hu_in, const float* __restrict__ hu0,
                        const float* __restrict__ ebar, const float* __restrict__ vbar,
                        const float* __restrict__ Wu, const float* __restrict__ bu,
                        float* __restrict__ hu_out, float* __restrict__ dout) {
    int idx = blockIdx.x * 256 + threadIdx.x;
    int m = idx >> 7, d = idx & 127;
    float acc = bu[d];
    const float* segs[4] = { hu_in + m*DD, hu0 + m*DD, ebar + m*DD, vbar + m*DD };
    for (int s = 0; s < 4; s++) {
        const float* x = segs[s];
        const float* W = Wu + (s*DD)*DD + d;
        for (int k = 0; k < DD; k++)
            acc = fmaf(x[k], W[k*DD], acc);
    }
    float v = fmaxf(acc, 0.f);
    hu_out[idx] = v;
    dout[idx] = v;
}

// ---------------- launch ----------------

extern "C" void kernel_launch(void* const* d_in, const int* in_sizes, int n_in,
                              void* d_out, int out_size, void* d_ws, size_t ws_size,
                              hipStream_t stream) {
    const float* atoms = (const float*)d_in[0];
    const float* bo    = (const float*)d_in[1];
    const float* Wfe   = (const float*)d_in[2];
    const float* bfe   = (const float*)d_in[3];
    const float* Wfv   = (const float*)d_in[4];
    const float* bfv   = (const float*)d_in[5];
    const float* Wfu   = (const float*)d_in[6];
    const float* bfu   = (const float*)d_in[7];
    const float* We    = (const float*)d_in[8];
    const float* be    = (const float*)d_in[9];
    const float* Wv    = (const float*)d_in[10];
    const float* bv    = (const float*)d_in[11];
    const float* Wu    = (const float*)d_in[12];
    const float* bu    = (const float*)d_in[13];
    const int* bsrc    = (const int*)d_in[14];
    const int* bdst    = (const int*)d_in[15];
    const int* amol    = (const int*)d_in[16];
    const int* bmol    = (const int*)d_in[17];

    char* p = (char*)d_ws;
    auto alloc = [&](size_t bytes) {
        char* r = p;
        p += (bytes + 255) & ~(size_t)255;
        return r;
    };
    unsigned short* he     = (unsigned short*)alloc((size_t)N_BONDS * DD * 2);
    unsigned short* ye0    = (unsigned short*)alloc((size_t)N_BONDS * DD * 2);
    unsigned short* hv     = (unsigned short*)alloc((size_t)N_ATOMS * DD * 2);
    unsigned short* yv0    = (unsigned short*)alloc((size_t)N_ATOMS * DD * 2);
    unsigned short* Zs     = (unsigned short*)alloc((size_t)N_ATOMS * DD * 2);
    unsigned short* Zd     = (unsigned short*)alloc((size_t)N_ATOMS * DD * 2);
    unsigned short* ebar_i = (unsigned short*)alloc((size_t)N_ATOMS * DD * 2);
    unsigned short* WeP    = (unsigned short*)alloc((size_t)640 * DD * 2);
    unsigned short* WvP    = (unsigned short*)alloc((size_t)512 * DD * 2);
    int* deg      = (int*)alloc((size_t)N_ATOMS * 4);
    int* rowptr   = (int*)alloc((size_t)(N_ATOMS + 1) * 4);
    int* cursor   = (int*)alloc((size_t)N_ATOMS * 4);
    int* adj      = (int*)alloc((size_t)2 * N_BONDS * 4);
    int* bmol_ptr = (int*)alloc((size_t)(N_MOLS + 1) * 4);
    int* amol_ptr = (int*)alloc((size_t)(N_MOLS + 1) * 4);
    float* node_sum = (float*)alloc((size_t)N_MOLS * DD * 4);
    float* hu0   = (float*)alloc((size_t)N_MOLS * DD * 4);
    float* huA   = (float*)alloc((size_t)N_MOLS * DD * 4);
    float* huB   = (float*)alloc((size_t)N_MOLS * DD * 4);
    float* ebar  = (float*)alloc((size_t)N_MOLS * DD * 4);
    float* vbar  = (float*)alloc((size_t)N_MOLS * DD * 4);
    float* yue   = (float*)alloc((size_t)N_MOLS * DD * 4);
    float* yuv   = (float*)alloc((size_t)N_MOLS * DD * 4);

    // ---- CSR + mol ranges ----
    hipMemsetAsync(deg, 0, (size_t)N_ATOMS * 4, stream);
    k_deg<<<N_BONDS/256, 256, 0, stream>>>(bsrc, bdst, deg);
    k_scan<<<1, 1024, 0, stream>>>(deg, rowptr, cursor);
    k_fill<<<N_BONDS/256, 256, 0, stream>>>(bsrc, bdst, cursor, adj);
    k_molptr<<<1, 1024, 0, stream>>>(bmol, N_BONDS, bmol_ptr);
    k_molptr<<<1, 1024, 0, stream>>>(amol, N_ATOMS, amol_ptr);

    // ---- weight packing ----
    k_pack_w<<<(640*DD)/256, 256, 0, stream>>>(We, WeP, 640);
    k_pack_w<<<(512*DD)/256, 256, 0, stream>>>(Wv, WvP, 512);

    // ---- init states + invariants ----
    k_init_edges<<<(N_BONDS*DD)/256, 256, 0, stream>>>(bo, Wfe, bfe, he);
    k_init_nodes<<<(N_ATOMS*DD)/256, 256, 0, stream>>>(atoms, Wfv, bfv, hv, node_sum);
    k_ye0<<<N_BONDS/128, 256, 0, stream>>>(bo, Wfe, bfe, WeP, ye0);
    k_xform<<<N_ATOMS/128, 256, 0, stream>>>(hv, WvP, 1, yv0);
    k_molsum_s<<<N_MOLS*2, 256, 0, stream>>>(hv, amol_ptr, node_sum, 2);
    k_mol_init<<<(N_MOLS*DD)/256, 256, 0, stream>>>(node_sum, Wfu, bfu, hu0);

    const float* hu_in = hu0; float* hu_out = huA;

    for (int r = 0; r < REPEAT; r++) {
        k_yrow2<<<(2*N_MOLS*DD)/256, 256, 0, stream>>>(hu_in, We, be, Wv, bv,
                                                       yue, yuv, ebar, vbar);
        k_zsd<<<N_ATOMS/128, 256, 0, stream>>>(hv, WeP, Zs, Zd);
        k_phi_e<<<N_BONDS/128, 256, 0, stream>>>(he, ye0, Zs, Zd, WeP, yue,
                                                 bsrc, bdst, bmol);
        k_ebar<<<N_ATOMS/16, 256, 0, stream>>>(he, rowptr, adj, ebar_i);
        k_molsum_s<<<N_MOLS*4, 256, 0, stream>>>(he, bmol_ptr, ebar, 4);
        k_phi_v<<<N_ATOMS/128, 256, 0, stream>>>(hv, ebar_i, yv0, WvP, yuv, amol);
        k_molsum_s<<<N_MOLS*2, 256, 0, stream>>>(hv, amol_ptr, vbar, 2);
        k_phi_u<<<(N_MOLS*DD)/256, 256, 0, stream>>>(hu_in, hu0, ebar, vbar, Wu, bu,
                                                     hu_out, (float*)d_out);

        hu_in = hu_out; hu_out = (hu_out == huA) ? huB : huA;
    }
}

// Round 10
// 523.196 us; speedup vs baseline: 1.4386x; 1.1415x over previous
//
#include <hip/hip_runtime.h>
#include <hip/hip_bf16.h>
#include <stdint.h>

#define N_ATOMS 65536
#define N_BONDS 131072
#define N_MOLS  512
#define D_IN    16
#define DD      128
#define REPEAT  3
#define PITCH   136   // LDS row pitch (bf16): 2-way max bank aliasing (free)

typedef __attribute__((ext_vector_type(8))) short s8b;
typedef __attribute__((ext_vector_type(4))) float f32x4;

__device__ __forceinline__ float us2f(unsigned short s) {
    unsigned int u = ((unsigned int)s) << 16;
    float f; __builtin_memcpy(&f, &u, 4); return f;
}
__device__ __forceinline__ unsigned short f2us(float f) {
    __hip_bfloat16 h = __float2bfloat16(f);
    unsigned short s; __builtin_memcpy(&s, &h, 2); return s;
}
__device__ __forceinline__ void acc8(float* a, uint4 v) {
    unsigned short w[8]; __builtin_memcpy(w, &v, 16);
#pragma unroll
    for (int j = 0; j < 8; j++) a[j] += us2f(w[j]);
}

// ---------------- one-time prep ----------------

// Pack W[K][128] fp32 -> bf16 fragment order: Wpk[(((c*4+ks)*4+quad)*128 + n)*8 + j]
__global__ void k_pack_w(const float* __restrict__ W, unsigned short* __restrict__ Wpk, int K) {
    int idx = blockIdx.x * 256 + threadIdx.x;     // K*128
    if (idx >= K * 128) return;
    int k = idx >> 7, n = idx & 127;
    int c = k >> 7, ks = (k >> 5) & 3, quad = (k >> 3) & 3, j = k & 7;
    int pidx = (((c * 4 + ks) * 4 + quad) * 128 + n) * 8 + j;
    Wpk[pidx] = f2us(W[k * 128 + n]);
}

__global__ void k_deg(const int* __restrict__ bsrc, const int* __restrict__ bdst,
                      int* __restrict__ deg) {
    int e = blockIdx.x * 256 + threadIdx.x;
    atomicAdd(&deg[bsrc[e]], 1);
    atomicAdd(&deg[bdst[e]], 1);
}

// parallel scan, phase 1: per-256-chunk sums (grid 256 x block 256)
__global__ void k_scan1(const int* __restrict__ deg, int* __restrict__ bsum) {
    __shared__ int red[256];
    int t = threadIdx.x;
    red[t] = deg[blockIdx.x * 256 + t];
    __syncthreads();
    for (int s = 128; s > 0; s >>= 1) {
        if (t < s) red[t] += red[t + s];
        __syncthreads();
    }
    if (t == 0) bsum[blockIdx.x] = red[0];
}

// phase 2: exclusive scan of 256 block sums (1 block x 256)
__global__ void k_scan2(const int* __restrict__ bsum, int* __restrict__ boff) {
    __shared__ int s[256];
    int t = threadIdx.x;
    s[t] = bsum[t];
    __syncthreads();
    if (t == 0) {
        int run = 0;
        for (int i = 0; i < 256; i++) { int v = s[i]; s[i] = run; run += v; }
    }
    __syncthreads();
    boff[t] = s[t];
}

// phase 3: per-block Hillis-Steele + offset, write rowptr & cursor (grid 256 x 256)
__global__ void k_scan3(const int* __restrict__ deg, const int* __restrict__ boff,
                        int* __restrict__ rowptr, int* __restrict__ cursor) {
    __shared__ int s[256];
    int t = threadIdx.x;
    int i = blockIdx.x * 256 + t;
    int d = deg[i];
    s[t] = d;
    __syncthreads();
    for (int off = 1; off < 256; off <<= 1) {
        int v = (t >= off) ? s[t - off] : 0;
        __syncthreads();
        s[t] += v;
        __syncthreads();
    }
    int val = boff[blockIdx.x] + s[t] - d;   // exclusive
    rowptr[i] = val;
    cursor[i] = val;
    if (i == N_ATOMS - 1) rowptr[N_ATOMS] = val + d;
}

__global__ void k_fill(const int* __restrict__ bsrc, const int* __restrict__ bdst,
                       int* __restrict__ cursor, int* __restrict__ adj) {
    int e = blockIdx.x * 256 + threadIdx.x;
    int p = atomicAdd(&cursor[bsrc[e]], 1); adj[p] = e;
    int q = atomicAdd(&cursor[bdst[e]], 1); adj[q] = e;
}

// both mol_ptr arrays in one launch: block 0 -> bonds, block 1 -> atoms
__global__ void k_molptr2(const int* __restrict__ bmol, const int* __restrict__ amol,
                          int* __restrict__ bptr, int* __restrict__ aptr) {
    int m = threadIdx.x;
    if (m > N_MOLS) return;
    const int* ids = blockIdx.x ? amol : bmol;
    int rows = blockIdx.x ? N_ATOMS : N_BONDS;
    int* out = blockIdx.x ? aptr : bptr;
    int lo = 0, hi = rows;
    while (lo < hi) {
        int mid = (lo + hi) >> 1;
        if (ids[mid] < m) lo = mid + 1; else hi = mid;
    }
    out[m] = lo;
}

// ---------------- init ----------------

// split per-molecule sum: S sub-ranges per mol; one atomic per col per block.
__global__ __launch_bounds__(256) void k_molsum_s(const unsigned short* __restrict__ x,
                                                  const int* __restrict__ mptr,
                                                  float* __restrict__ out, int S) {
    __shared__ float red[16 * 128];
    int m = blockIdx.x / S, s = blockIdx.x - m * S;
    int b = mptr[m], e = mptr[m + 1];
    int len = (e - b + S - 1) / S;
    int r0 = b + s * len;
    int r1 = min(r0 + len, e);
    int rl = threadIdx.x >> 4, g = threadIdx.x & 15;
    float acc[8] = {0,0,0,0,0,0,0,0};
    for (int r = r0 + rl; r < r1; r += 16)
        acc8(acc, *reinterpret_cast<const uint4*>(x + (size_t)r * DD + g * 8));
#pragma unroll
    for (int j = 0; j < 8; j++) red[rl * 128 + g * 8 + j] = acc[j];
    __syncthreads();
    if (threadIdx.x < 128) {
        int col = threadIdx.x;
        float sum = 0.f;
#pragma unroll
        for (int i = 0; i < 16; i++) sum += red[i * 128 + col];
        atomicAdd(&out[(size_t)m * DD + col], sum);
    }
}

__global__ void k_mol_init(const float* __restrict__ ns, const float* __restrict__ Wfu,
                           const float* __restrict__ bfu, float* __restrict__ hu0) {
    int idx = blockIdx.x * 256 + threadIdx.x;
    int m = idx >> 7, d = idx & 127;
    float acc = bfu[d];
    for (int k = 0; k < DD; k++)
        acc = fmaf(ns[m*DD + k], Wfu[k*DD + d], acc);
    hu0[idx] = fmaxf(acc, 0.f);
}

// fused per-round: zero ebar/vbar + tiny GEMMs yue/yuv
__global__ void k_yrow2(const float* __restrict__ hu,
                        const float* __restrict__ We, const float* __restrict__ be,
                        const float* __restrict__ Wv, const float* __restrict__ bv,
                        float* __restrict__ yue, float* __restrict__ yuv,
                        float* __restrict__ ebar, float* __restrict__ vbar) {
    int idx = blockIdx.x * 256 + threadIdx.x;   // 2*M*D
    if (idx < N_MOLS * DD) ebar[idx] = 0.f;
    else                   vbar[idx - N_MOLS * DD] = 0.f;
    int half = idx >= N_MOLS * DD;
    int md = half ? idx - N_MOLS * DD : idx;
    int m = md >> 7, d = md & 127;
    const float* W  = half ? Wv + 384 * DD : We + 512 * DD;
    float acc = half ? bv[d] : be[d];
    for (int k = 0; k < DD; k++)
        acc = fmaf(hu[m*DD + k], W[k*DD + d], acc);
    (half ? yuv : yue)[md] = acc;
}

// ---------------- one-time: he = he0 (rank-1) AND ye0 = he0 @ We[128:256] ----------------
__global__ __launch_bounds__(256) void k_ye0(
        const float* __restrict__ bo, const float* __restrict__ Wfe,
        const float* __restrict__ bfe, const unsigned short* __restrict__ Wpk,
        unsigned short* __restrict__ he, unsigned short* __restrict__ ye0) {
    __shared__ __align__(16) unsigned short xs[128 * PITCH];
    __shared__ float sbo[128];
    int tid = threadIdx.x;
    int e0 = blockIdx.x * 128;
    if (tid < 128) sbo[tid] = bo[e0 + tid];
    int wv = tid >> 6, lane = tid & 63, quad = lane >> 4, l15 = lane & 15;
    f32x4 acc[8][2];
#pragma unroll
    for (int mt = 0; mt < 8; mt++) {
        acc[mt][0] = (f32x4){0.f,0.f,0.f,0.f};
        acc[mt][1] = (f32x4){0.f,0.f,0.f,0.f};
    }
    __syncthreads();
    for (int t = 0; t < 8; t++) {
        int u = tid + t * 256;
        int i = u >> 4, g = (u & 15) * 8;
        float b = sbo[i];
        unsigned short tmp[8];
#pragma unroll
        for (int j = 0; j < 8; j++)
            tmp[j] = f2us(fmaxf(fmaf(b, Wfe[g + j], bfe[g + j]), 0.f));
        uint4 val; __builtin_memcpy(&val, tmp, 16);
        *reinterpret_cast<uint4*>(&xs[i * PITCH + g]) = val;
        *reinterpret_cast<uint4*>(he + (size_t)(e0 + i) * DD + g) = val;  // he init fused
    }
    __syncthreads();
#pragma unroll
    for (int ks = 0; ks < 4; ks++) {
        const unsigned short* wb = Wpk + ((1 * 4 + ks) * 4 + quad) * 1024 + (wv * 32 + l15) * 8;
        s8b b0 = *reinterpret_cast<const s8b*>(wb);
        s8b b1 = *reinterpret_cast<const s8b*>(wb + 128);
#pragma unroll
        for (int mt = 0; mt < 8; mt++) {
            s8b afr = *reinterpret_cast<const s8b*>(&xs[(mt*16 + l15) * PITCH + ks*32 + quad*8]);
            acc[mt][0] = __builtin_amdgcn_mfma_f32_16x16x32_bf16(afr, b0, acc[mt][0], 0, 0, 0);
            acc[mt][1] = __builtin_amdgcn_mfma_f32_16x16x32_bf16(afr, b1, acc[mt][1], 0, 0, 0);
        }
    }
#pragma unroll
    for (int mt = 0; mt < 8; mt++)
#pragma unroll
        for (int r = 0; r < 4; r++) {
            int row = e0 + mt*16 + quad*4 + r;
#pragma unroll
            for (int nt = 0; nt < 2; nt++) {
                int col = wv*32 + nt*16 + l15;
                ye0[(size_t)row * DD + col] = f2us(acc[mt][nt][r]);
            }
        }
}

// ---------------- one-time: hv = relu(atoms@Wfv+bfv) AND yv0 = hv @ Wv[128:256] ----------------
__global__ __launch_bounds__(256) void k_nodes_f(
        const float* __restrict__ atoms, const float* __restrict__ Wfv,
        const float* __restrict__ bfv, const unsigned short* __restrict__ Wpk,
        unsigned short* __restrict__ hv, unsigned short* __restrict__ yv0,
        float* __restrict__ node_sum) {
    __shared__ __align__(16) unsigned short xs[128 * PITCH];
    int tid = threadIdx.x;
    int gid = blockIdx.x * 256 + tid;
    if (gid < N_MOLS * DD) node_sum[gid] = 0.f;     // zero for molsum accumulate
    int n0 = blockIdx.x * 128;
    int wv = tid >> 6, lane = tid & 63, quad = lane >> 4, l15 = lane & 15;
    f32x4 acc[8][2];
#pragma unroll
    for (int mt = 0; mt < 8; mt++) {
        acc[mt][0] = (f32x4){0.f,0.f,0.f,0.f};
        acc[mt][1] = (f32x4){0.f,0.f,0.f,0.f};
    }
    for (int t = 0; t < 8; t++) {
        int u = tid + t * 256;
        int i = u >> 4, g = (u & 15) * 8;
        int row = n0 + i;
        float a[D_IN];
#pragma unroll
        for (int k = 0; k < D_IN; k++) a[k] = atoms[(size_t)row * D_IN + k];
        unsigned short tmp[8];
#pragma unroll
        for (int j = 0; j < 8; j++) {
            float acc1 = bfv[g + j];
#pragma unroll
            for (int k = 0; k < D_IN; k++)
                acc1 = fmaf(a[k], Wfv[k*DD + g + j], acc1);
            tmp[j] = f2us(fmaxf(acc1, 0.f));
        }
        uint4 val; __builtin_memcpy(&val, tmp, 16);
        *reinterpret_cast<uint4*>(&xs[i * PITCH + g]) = val;
        *reinterpret_cast<uint4*>(hv + (size_t)row * DD + g) = val;
    }
    __syncthreads();
#pragma unroll
    for (int ks = 0; ks < 4; ks++) {
        const unsigned short* wb = Wpk + ((1 * 4 + ks) * 4 + quad) * 1024 + (wv * 32 + l15) * 8;
        s8b b0 = *reinterpret_cast<const s8b*>(wb);
        s8b b1 = *reinterpret_cast<const s8b*>(wb + 128);
#pragma unroll
        for (int mt = 0; mt < 8; mt++) {
            s8b afr = *reinterpret_cast<const s8b*>(&xs[(mt*16 + l15) * PITCH + ks*32 + quad*8]);
            acc[mt][0] = __builtin_amdgcn_mfma_f32_16x16x32_bf16(afr, b0, acc[mt][0], 0, 0, 0);
            acc[mt][1] = __builtin_amdgcn_mfma_f32_16x16x32_bf16(afr, b1, acc[mt][1], 0, 0, 0);
        }
    }
#pragma unroll
    for (int mt = 0; mt < 8; mt++)
#pragma unroll
        for (int r = 0; r < 4; r++) {
            int row = n0 + mt*16 + quad*4 + r;
#pragma unroll
            for (int nt = 0; nt < 2; nt++) {
                int col = wv*32 + nt*16 + l15;
                yv0[(size_t)row * DD + col] = f2us(acc[mt][nt][r]);
            }
        }
}

// ---------------- per-round: Zs = hv@We[256:384], Zd = hv@We[384:512] ----------------
__global__ __launch_bounds__(256) void k_zsd(
        const unsigned short* __restrict__ hv, const unsigned short* __restrict__ Wpk,
        unsigned short* __restrict__ Zs, unsigned short* __restrict__ Zd) {
    __shared__ __align__(16) unsigned short xs[128 * PITCH];
    int tid = threadIdx.x;
    int n0 = blockIdx.x * 128;
    int wv = tid >> 6, lane = tid & 63, quad = lane >> 4, l15 = lane & 15;
    f32x4 aS[8][2], aD[8][2];
#pragma unroll
    for (int mt = 0; mt < 8; mt++) {
        aS[mt][0] = (f32x4){0.f,0.f,0.f,0.f}; aS[mt][1] = (f32x4){0.f,0.f,0.f,0.f};
        aD[mt][0] = (f32x4){0.f,0.f,0.f,0.f}; aD[mt][1] = (f32x4){0.f,0.f,0.f,0.f};
    }
    for (int t = 0; t < 8; t++) {
        int u = tid + t * 256;
        int i = u >> 4, g = (u & 15) * 8;
        *reinterpret_cast<uint4*>(&xs[i * PITCH + g]) =
            *reinterpret_cast<const uint4*>(hv + (size_t)(n0 + i) * DD + g);
    }
    __syncthreads();
#pragma unroll
    for (int ks = 0; ks < 4; ks++) {
        const unsigned short* wbS = Wpk + ((2 * 4 + ks) * 4 + quad) * 1024 + (wv * 32 + l15) * 8;
        const unsigned short* wbD = Wpk + ((3 * 4 + ks) * 4 + quad) * 1024 + (wv * 32 + l15) * 8;
        s8b s0 = *reinterpret_cast<const s8b*>(wbS);
        s8b s1 = *reinterpret_cast<const s8b*>(wbS + 128);
        s8b d0 = *reinterpret_cast<const s8b*>(wbD);
        s8b d1 = *reinterpret_cast<const s8b*>(wbD + 128);
#pragma unroll
        for (int mt = 0; mt < 8; mt++) {
            s8b afr = *reinterpret_cast<const s8b*>(&xs[(mt*16 + l15) * PITCH + ks*32 + quad*8]);
            aS[mt][0] = __builtin_amdgcn_mfma_f32_16x16x32_bf16(afr, s0, aS[mt][0], 0, 0, 0);
            aS[mt][1] = __builtin_amdgcn_mfma_f32_16x16x32_bf16(afr, s1, aS[mt][1], 0, 0, 0);
            aD[mt][0] = __builtin_amdgcn_mfma_f32_16x16x32_bf16(afr, d0, aD[mt][0], 0, 0, 0);
            aD[mt][1] = __builtin_amdgcn_mfma_f32_16x16x32_bf16(afr, d1, aD[mt][1], 0, 0, 0);
        }
    }
#pragma unroll
    for (int mt = 0; mt < 8; mt++)
#pragma unroll
        for (int r = 0; r < 4; r++) {
            int row = n0 + mt*16 + quad*4 + r;
#pragma unroll
            for (int nt = 0; nt < 2; nt++) {
                int col = wv*32 + nt*16 + l15;
                Zs[(size_t)row * DD + col] = f2us(aS[mt][nt][r]);
                Zd[(size_t)row * DD + col] = f2us(aD[mt][nt][r]);
            }
        }
}

// ---------------- phi_e: 1 MFMA chunk + gathered epilogue ----------------
// he[e] <- relu( he@We[0:128] + ye0[e] + Zs[src] + Zd[dst] + yue[bmol[e]] ), in place.
__global__ __launch_bounds__(256) void k_phi_e(
        unsigned short* __restrict__ he, const unsigned short* __restrict__ ye0,
        const unsigned short* __restrict__ Zs, const unsigned short* __restrict__ Zd,
        const unsigned short* __restrict__ Wpk, const float* __restrict__ yue,
        const int* __restrict__ bsrc, const int* __restrict__ bdst,
        const int* __restrict__ bmol) {
    __shared__ __align__(16) unsigned short xs[128 * PITCH];
    __shared__ int ssrc[128], sdst[128], smol[128];
    int tid = threadIdx.x;
    int e0 = blockIdx.x * 128;
    if (tid < 128) {
        ssrc[tid] = bsrc[e0 + tid];
        sdst[tid] = bdst[e0 + tid];
        smol[tid] = bmol[e0 + tid];
    }
    int wv = tid >> 6, lane = tid & 63, quad = lane >> 4, l15 = lane & 15;
    f32x4 acc[8][2];
#pragma unroll
    for (int mt = 0; mt < 8; mt++) {
        acc[mt][0] = (f32x4){0.f,0.f,0.f,0.f};
        acc[mt][1] = (f32x4){0.f,0.f,0.f,0.f};
    }
    // stage he rows (no dependency on ssrc)
    for (int t = 0; t < 8; t++) {
        int u = tid + t * 256;
        int i = u >> 4, g = (u & 15) * 8;
        *reinterpret_cast<uint4*>(&xs[i * PITCH + g]) =
            *reinterpret_cast<const uint4*>(he + (size_t)(e0 + i) * DD + g);
    }
    __syncthreads();
#pragma unroll
    for (int ks = 0; ks < 4; ks++) {
        const unsigned short* wb = Wpk + ((0 * 4 + ks) * 4 + quad) * 1024 + (wv * 32 + l15) * 8;
        s8b b0 = *reinterpret_cast<const s8b*>(wb);
        s8b b1 = *reinterpret_cast<const s8b*>(wb + 128);
#pragma unroll
        for (int mt = 0; mt < 8; mt++) {
            s8b afr = *reinterpret_cast<const s8b*>(&xs[(mt*16 + l15) * PITCH + ks*32 + quad*8]);
            acc[mt][0] = __builtin_amdgcn_mfma_f32_16x16x32_bf16(afr, b0, acc[mt][0], 0, 0, 0);
            acc[mt][1] = __builtin_amdgcn_mfma_f32_16x16x32_bf16(afr, b1, acc[mt][1], 0, 0, 0);
        }
    }
    __syncthreads();   // xs free for reuse
    // stage ysum = ye0 + Zs[src] + Zd[dst] + yue[mol] into xs (bf16)
    for (int t = 0; t < 8; t++) {
        int u = tid + t * 256;
        int i = u >> 4, g = (u & 15) * 8;
        float s[8] = {0,0,0,0,0,0,0,0};
        acc8(s, *reinterpret_cast<const uint4*>(ye0 + (size_t)(e0 + i) * DD + g));
        acc8(s, *reinterpret_cast<const uint4*>(Zs  + (size_t)ssrc[i] * DD + g));
        acc8(s, *reinterpret_cast<const uint4*>(Zd  + (size_t)sdst[i] * DD + g));
        const float* yr = yue + (size_t)smol[i] * DD + g;
        float4 y0 = *reinterpret_cast<const float4*>(yr);
        float4 y1 = *reinterpret_cast<const float4*>(yr + 4);
        s[0] += y0.x; s[1] += y0.y; s[2] += y0.z; s[3] += y0.w;
        s[4] += y1.x; s[5] += y1.y; s[6] += y1.z; s[7] += y1.w;
        unsigned short tmp[8];
#pragma unroll
        for (int j = 0; j < 8; j++) tmp[j] = f2us(s[j]);
        uint4 val; __builtin_memcpy(&val, tmp, 16);
        *reinterpret_cast<uint4*>(&xs[i * PITCH + g]) = val;
    }
    __syncthreads();
    // epilogue: C/D layout col=lane&15, row=quad*4+reg
#pragma unroll
    for (int mt = 0; mt < 8; mt++)
#pragma unroll
        for (int r = 0; r < 4; r++) {
            int rl = mt*16 + quad*4 + r;
#pragma unroll
            for (int nt = 0; nt < 2; nt++) {
                int col = wv*32 + nt*16 + l15;
                float v = acc[mt][nt][r] + us2f(xs[rl * PITCH + col]);
                he[(size_t)(e0 + rl) * DD + col] = f2us(fmaxf(v, 0.f));
            }
        }
}

// ---------------- e_bar_i gather (CSR, vectorized, unroll-4) ----------------
__global__ __launch_bounds__(256) void k_ebar(const unsigned short* __restrict__ he,
                                              const int* __restrict__ rowptr,
                                              const int* __restrict__ adj,
                                              unsigned short* __restrict__ ebar_i) {
    int n = blockIdx.x * 16 + (threadIdx.x >> 4);
    int g = threadIdx.x & 15;
    int b = rowptr[n], e = rowptr[n + 1];
    float acc[8] = {0,0,0,0,0,0,0,0};
    int j = b;
    for (; j + 3 < e; j += 4) {
        uint4 v0 = *reinterpret_cast<const uint4*>(he + (size_t)adj[j]     * DD + g * 8);
        uint4 v1 = *reinterpret_cast<const uint4*>(he + (size_t)adj[j + 1] * DD + g * 8);
        uint4 v2 = *reinterpret_cast<const uint4*>(he + (size_t)adj[j + 2] * DD + g * 8);
        uint4 v3 = *reinterpret_cast<const uint4*>(he + (size_t)adj[j + 3] * DD + g * 8);
        acc8(acc, v0); acc8(acc, v1); acc8(acc, v2); acc8(acc, v3);
    }
    for (; j < e; j++)
        acc8(acc, *reinterpret_cast<const uint4*>(he + (size_t)adj[j] * DD + g * 8));
    unsigned short o[8];
#pragma unroll
    for (int k = 0; k < 8; k++) o[k] = f2us(acc[k]);
    uint4 ov; __builtin_memcpy(&ov, o, 16);
    *reinterpret_cast<uint4*>(ebar_i + (size_t)n * DD + g * 8) = ov;
}

// ---------------- phi_v: 2 MFMA chunks + epilogue ----------------
// hv[n] <- relu( hv@Wv[0:128] + ebar_i@Wv[256:384] + yv0[n] + yuv[amol[n]] ), in place.
__global__ __launch_bounds__(256) void k_phi_v(
        unsigned short* __restrict__ hv, const unsigned short* __restrict__ ebar_i,
        const unsigned short* __restrict__ yv0,
        const unsigned short* __restrict__ Wpk, const float* __restrict__ yuv,
        const int* __restrict__ amol) {
    __shared__ __align__(16) unsigned short xs[128 * PITCH];
    __shared__ int smol[128];
    int tid = threadIdx.x;
    int n0 = blockIdx.x * 128;
    if (tid < 128) smol[tid] = amol[n0 + tid];
    int wv = tid >> 6, lane = tid & 63, quad = lane >> 4, l15 = lane & 15;
    f32x4 acc[8][2];
#pragma unroll
    for (int mt = 0; mt < 8; mt++) {
        acc[mt][0] = (f32x4){0.f,0.f,0.f,0.f};
        acc[mt][1] = (f32x4){0.f,0.f,0.f,0.f};
    }
    const unsigned short* bases[2] = { hv + (size_t)n0 * DD, ebar_i + (size_t)n0 * DD };
    const int wcs[2] = {0, 2};
    for (int c = 0; c < 2; c++) {
        if (c) __syncthreads();
        for (int t = 0; t < 8; t++) {
            int u = tid + t * 256;
            int i = u >> 4, g = (u & 15) * 8;
            *reinterpret_cast<uint4*>(&xs[i * PITCH + g]) =
                *reinterpret_cast<const uint4*>(bases[c] + (size_t)i * DD + g);
        }
        __syncthreads();
        int WC = wcs[c];
#pragma unroll
        for (int ks = 0; ks < 4; ks++) {
            const unsigned short* wb = Wpk + ((WC * 4 + ks) * 4 + quad) * 1024 + (wv * 32 + l15) * 8;
            s8b b0 = *reinterpret_cast<const s8b*>(wb);
            s8b b1 = *reinterpret_cast<const s8b*>(wb + 128);
#pragma unroll
            for (int mt = 0; mt < 8; mt++) {
                s8b afr = *reinterpret_cast<const s8b*>(&xs[(mt*16 + l15) * PITCH + ks*32 + quad*8]);
                acc[mt][0] = __builtin_amdgcn_mfma_f32_16x16x32_bf16(afr, b0, acc[mt][0], 0, 0, 0);
                acc[mt][1] = __builtin_amdgcn_mfma_f32_16x16x32_bf16(afr, b1, acc[mt][1], 0, 0, 0);
            }
        }
    }
    __syncthreads();   // reuse xs for ysum
    for (int t = 0; t < 8; t++) {
        int u = tid + t * 256;
        int i = u >> 4, g = (u & 15) * 8;
        float s[8] = {0,0,0,0,0,0,0,0};
        acc8(s, *reinterpret_cast<const uint4*>(yv0 + (size_t)(n0 + i) * DD + g));
        const float* yr = yuv + (size_t)smol[i] * DD + g;
        float4 y0 = *reinterpret_cast<const float4*>(yr);
        float4 y1 = *reinterpret_cast<const float4*>(yr + 4);
        s[0] += y0.x; s[1] += y0.y; s[2] += y0.z; s[3] += y0.w;
        s[4] += y1.x; s[5] += y1.y; s[6] += y1.z; s[7] += y1.w;
        unsigned short tmp[8];
#pragma unroll
        for (int j = 0; j < 8; j++) tmp[j] = f2us(s[j]);
        uint4 val; __builtin_memcpy(&val, tmp, 16);
        *reinterpret_cast<uint4*>(&xs[i * PITCH + g]) = val;
    }
    __syncthreads();
#pragma unroll
    for (int mt = 0; mt < 8; mt++)
#pragma unroll
        for (int r = 0; r < 4; r++) {
            int rl = mt*16 + quad*4 + r;
#pragma unroll
            for (int nt = 0; nt < 2; nt++) {
                int col = wv*32 + nt*16 + l15;
                float v = acc[mt][nt][r] + us2f(xs[rl * PITCH + col]);
                hv[(size_t)(n0 + rl) * DD + col] = f2us(fmaxf(v, 0.f));
            }
        }
}

// ---------------- phi_u ----------------
__global__ void k_phi_u(const float* __restrict__ hu_in, const float* __restrict__ hu0,
                        const float* __restrict__ ebar, const float* __restrict__ vbar,
                        const float* __restrict__ Wu, const float* __restrict__ bu,
                        float* __restrict__ hu_out, float* __restrict__ dout) {
    int idx = blockIdx.x * 256 + threadIdx.x;
    int m = idx >> 7, d = idx & 127;
    float acc = bu[d];
    const float* segs[4] = { hu_in + m*DD, hu0 + m*DD, ebar + m*DD, vbar + m*DD };
    for (int s = 0; s < 4; s++) {
        const float* x = segs[s];
        const float* W = Wu + (s*DD)*DD + d;
        for (int k = 0; k < DD; k++)
            acc = fmaf(x[k], W[k*DD], acc);
    }
    float v = fmaxf(acc, 0.f);
    hu_out[idx] = v;
    dout[idx] = v;
}

// ---------------- launch ----------------

extern "C" void kernel_launch(void* const* d_in, const int* in_sizes, int n_in,
                              void* d_out, int out_size, void* d_ws, size_t ws_size,
                              hipStream_t stream) {
    const float* atoms = (const float*)d_in[0];
    const float* bo    = (const float*)d_in[1];
    const float* Wfe   = (const float*)d_in[2];
    const float* bfe   = (const float*)d_in[3];
    const float* Wfv   = (const float*)d_in[4];
    const float* bfv   = (const float*)d_in[5];
    const float* Wfu   = (const float*)d_in[6];
    const float* bfu   = (const float*)d_in[7];
    const float* We    = (const float*)d_in[8];
    const float* be    = (const float*)d_in[9];
    const float* Wv    = (const float*)d_in[10];
    const float* bv    = (const float*)d_in[11];
    const float* Wu    = (const float*)d_in[12];
    const float* bu    = (const float*)d_in[13];
    const int* bsrc    = (const int*)d_in[14];
    const int* bdst    = (const int*)d_in[15];
    const int* amol    = (const int*)d_in[16];
    const int* bmol    = (const int*)d_in[17];

    char* p = (char*)d_ws;
    auto alloc = [&](size_t bytes) {
        char* r = p;
        p += (bytes + 255) & ~(size_t)255;
        return r;
    };
    unsigned short* he     = (unsigned short*)alloc((size_t)N_BONDS * DD * 2);
    unsigned short* ye0    = (unsigned short*)alloc((size_t)N_BONDS * DD * 2);
    unsigned short* hv     = (unsigned short*)alloc((size_t)N_ATOMS * DD * 2);
    unsigned short* yv0    = (unsigned short*)alloc((size_t)N_ATOMS * DD * 2);
    unsigned short* Zs     = (unsigned short*)alloc((size_t)N_ATOMS * DD * 2);
    unsigned short* Zd     = (unsigned short*)alloc((size_t)N_ATOMS * DD * 2);
    unsigned short* ebar_i = (unsigned short*)alloc((size_t)N_ATOMS * DD * 2);
    unsigned short* WeP    = (unsigned short*)alloc((size_t)640 * DD * 2);
    unsigned short* WvP    = (unsigned short*)alloc((size_t)512 * DD * 2);
    int* deg      = (int*)alloc((size_t)N_ATOMS * 4);
    int* rowptr   = (int*)alloc((size_t)(N_ATOMS + 1) * 4);
    int* cursor   = (int*)alloc((size_t)N_ATOMS * 4);
    int* adj      = (int*)alloc((size_t)2 * N_BONDS * 4);
    int* bmol_ptr = (int*)alloc((size_t)(N_MOLS + 1) * 4);
    int* amol_ptr = (int*)alloc((size_t)(N_MOLS + 1) * 4);
    int* bsum     = (int*)alloc((size_t)256 * 4);
    int* boff     = (int*)alloc((size_t)256 * 4);
    float* node_sum = (float*)alloc((size_t)N_MOLS * DD * 4);
    float* hu0   = (float*)alloc((size_t)N_MOLS * DD * 4);
    float* huA   = (float*)alloc((size_t)N_MOLS * DD * 4);
    float* huB   = (float*)alloc((size_t)N_MOLS * DD * 4);
    float* ebar  = (float*)alloc((size_t)N_MOLS * DD * 4);
    float* vbar  = (float*)alloc((size_t)N_MOLS * DD * 4);
    float* yue   = (float*)alloc((size_t)N_MOLS * DD * 4);
    float* yuv   = (float*)alloc((size_t)N_MOLS * DD * 4);

    // ---- CSR + mol ranges ----
    hipMemsetAsync(deg, 0, (size_t)N_ATOMS * 4, stream);
    k_deg<<<N_BONDS/256, 256, 0, stream>>>(bsrc, bdst, deg);
    k_scan1<<<256, 256, 0, stream>>>(deg, bsum);
    k_scan2<<<1, 256, 0, stream>>>(bsum, boff);
    k_scan3<<<256, 256, 0, stream>>>(deg, boff, rowptr, cursor);
    k_fill<<<N_BONDS/256, 256, 0, stream>>>(bsrc, bdst, cursor, adj);
    k_molptr2<<<2, 1024, 0, stream>>>(bmol, amol, bmol_ptr, amol_ptr);

    // ---- weight packing ----
    k_pack_w<<<(640*DD)/256, 256, 0, stream>>>(We, WeP, 640);
    k_pack_w<<<(512*DD)/256, 256, 0, stream>>>(Wv, WvP, 512);

    // ---- init states + invariants (fused) ----
    k_ye0<<<N_BONDS/128, 256, 0, stream>>>(bo, Wfe, bfe, WeP, he, ye0);
    k_nodes_f<<<N_ATOMS/128, 256, 0, stream>>>(atoms, Wfv, bfv, WvP, hv, yv0, node_sum);
    k_molsum_s<<<N_MOLS*2, 256, 0, stream>>>(hv, amol_ptr, node_sum, 2);
    k_mol_init<<<(N_MOLS*DD)/256, 256, 0, stream>>>(node_sum, Wfu, bfu, hu0);

    const float* hu_in = hu0; float* hu_out = huA;

    for (int r = 0; r < REPEAT; r++) {
        k_yrow2<<<(2*N_MOLS*DD)/256, 256, 0, stream>>>(hu_in, We, be, Wv, bv,
                                                       yue, yuv, ebar, vbar);
        k_zsd<<<N_ATOMS/128, 256, 0, stream>>>(hv, WeP, Zs, Zd);
        k_phi_e<<<N_BONDS/128, 256, 0, stream>>>(he, ye0, Zs, Zd, WeP, yue,
                                                 bsrc, bdst, bmol);
        k_ebar<<<N_ATOMS/16, 256, 0, stream>>>(he, rowptr, adj, ebar_i);
        k_molsum_s<<<N_MOLS*4, 256, 0, stream>>>(he, bmol_ptr, ebar, 4);
        k_phi_v<<<N_ATOMS/128, 256, 0, stream>>>(hv, ebar_i, yv0, WvP, yuv, amol);
        k_molsum_s<<<N_MOLS*2, 256, 0, stream>>>(hv, amol_ptr, vbar, 2);
        k_phi_u<<<(N_MOLS*DD)/256, 256, 0, stream>>>(hu_in, hu0, ebar, vbar, Wu, bu,
                                                     hu_out, (float*)d_out);

        hu_in = hu_out; hu_out = (hu_out == huA) ? huB : huA;
    }
}